// Round 1
// 332.044 us; speedup vs baseline: 1.0590x; 1.0590x over previous
//
#include <hip/hip_runtime.h>

typedef __attribute__((ext_vector_type(8))) __bf16 bf16x8;
typedef __attribute__((ext_vector_type(4))) float f32x4;
typedef __attribute__((ext_vector_type(4))) short short4v;

#define MFMA16(a,b,c)  __builtin_amdgcn_mfma_f32_16x16x32_bf16((a),(b),(c),0,0,0)
#define MFMA16K(a,b,c) __builtin_amdgcn_mfma_f32_16x16x16bf16_1k((a),(b),(c),0,0,0)

__device__ __forceinline__ short f2bf(float f){
  union { float f; unsigned u; } x; x.f = f;
  return (short)((x.u + 0x7fffu + ((x.u >> 16) & 1u)) >> 16);
}
__device__ __forceinline__ unsigned bits(float f){
  union { float f; unsigned u; } x; x.f = f; return x.u;
}

__device__ __forceinline__ void gld16(void* lds, const void* g){
  __builtin_amdgcn_global_load_lds(
      (const __attribute__((address_space(1))) unsigned*)g,
      (__attribute__((address_space(3))) unsigned*)lds, 16, 0, 0);
}

// ---------------- elementwise converts / transposes ----------------

__global__ __launch_bounds__(256) void k_cvt8(const float* __restrict__ x,
                                              short* __restrict__ xb){
  long i = (long)blockIdx.x * 256 + threadIdx.x;       // groups of 8
  const float4* xv = (const float4*)x;
  float4 a = xv[2*i], c = xv[2*i+1];
  short s[8] = {f2bf(a.x),f2bf(a.y),f2bf(a.z),f2bf(a.w),
                f2bf(c.x),f2bf(c.y),f2bf(c.z),f2bf(c.w)};
  *(uint4*)&xb[8*i] = *(uint4*)s;
}

// W fp32 [2048][N] row-major -> Wt bf16 [N][2048]
__global__ void k_wt(const float* __restrict__ W, short* __restrict__ Wt, int N){
  __shared__ float tile[32][33];
  int tx = threadIdx.x, ty = threadIdx.y;
  int k0 = blockIdx.y*32, n0 = blockIdx.x*32;
  for (int j=0;j<32;j+=8)
    tile[ty+j][tx] = W[(size_t)(k0+ty+j)*N + n0 + tx];
  __syncthreads();
  for (int j=0;j<32;j+=8)
    Wt[(size_t)(n0+ty+j)*2048 + k0 + tx] = f2bf(tile[tx][ty+j]);
}

__global__ void k_bias(const float* __restrict__ bq, const float* __restrict__ bk,
                       const float* __restrict__ bv, float* __restrict__ outb){
  int i = blockIdx.x*256 + threadIdx.x;   // 0..3071
  float v = (i < 2048) ? bq[i] : (i < 2560 ? bk[i-2048] : bv[i-2560]);
  outb[i] = v;
}

// v-part of qkv (bf16, rows 4096, cols 2560..3071 of ld 3072) -> Vt[b][kvh][d][t]
__global__ void k_vt(const short* __restrict__ qkv, short* __restrict__ Vt){
  __shared__ short tile[32][33];
  int tx = threadIdx.x, ty = threadIdx.y;
  int t0 = blockIdx.x*32, c0 = blockIdx.y*32;
  for (int j=0;j<32;j+=8)
    tile[ty+j][tx] = qkv[(size_t)(t0+ty+j)*3072 + 2560 + c0 + tx];
  __syncthreads();
  int b = t0 >> 11, t_in_b = t0 & 2047;
  for (int j=0;j<32;j+=8){
    int col = c0 + ty + j;               // 0..511
    int kvh = col >> 7, d = col & 127;
    Vt[((size_t)((b*4 + kvh)*128 + d))*2048 + t_in_b + tx] = tile[tx][ty+j];
  }
}

// ---------------- m97-style GEMM: C = A * Bt^T + bias ----------------
template<int OUT_BF16>
__global__ __launch_bounds__(256) void gemm_bt(const short* __restrict__ A,
    const short* __restrict__ Bt, const float* __restrict__ bias,
    void* __restrict__ Cv, int M, int N, int K){
  __shared__ short As[128*32];
  __shared__ short Bs[128*32];
  const int tid = threadIdx.x;
  const int w = tid >> 6, lane = tid & 63, l15 = lane & 15, quad = lane >> 4;
  const int wr = w >> 1, wc = w & 1;
  const int m0 = blockIdx.y*128, n0 = blockIdx.x*128;
  const int lrow = lane >> 2, lcol = (lane & 3)*8;
  const short* Ag = A  + (size_t)(m0 + w*32 + lrow)*K + lcol;
  const short* Bg = Bt + (size_t)(n0 + w*32 + lrow)*K + lcol;
  short* AsW0 = &As[(w*32)*32];
  short* AsW1 = &As[(w*32+16)*32];
  short* BsW0 = &Bs[(w*32)*32];
  short* BsW1 = &Bs[(w*32+16)*32];
  const size_t r16K = (size_t)16*K;
  f32x4 acc[4][4] = {};
  for (int kt = 0; kt < K; kt += 32){
    gld16(AsW0, Ag + kt);
    gld16(AsW1, Ag + kt + r16K);
    gld16(BsW0, Bg + kt);
    gld16(BsW1, Bg + kt + r16K);
    __syncthreads();
    bf16x8 af[4], bfr[4];
#pragma unroll
    for (int i=0;i<4;i++){
      af[i]  = *(const bf16x8*)&As[(wr*64 + i*16 + l15)*32 + quad*8];
      bfr[i] = *(const bf16x8*)&Bs[(wc*64 + i*16 + l15)*32 + quad*8];
    }
#pragma unroll
    for (int mi=0;mi<4;mi++)
#pragma unroll
      for (int nj=0;nj<4;nj++)
        acc[mi][nj] = MFMA16(af[mi], bfr[nj], acc[mi][nj]);
    __syncthreads();
  }
  float bv[4];
#pragma unroll
  for (int nj=0;nj<4;nj++) bv[nj] = bias[n0 + wc*64 + nj*16 + l15];
#pragma unroll
  for (int mi=0;mi<4;mi++){
    int row = m0 + wr*64 + mi*16 + quad*4;
#pragma unroll
    for (int nj=0;nj<4;nj++){
      int col = n0 + wc*64 + nj*16 + l15;
#pragma unroll
      for (int r=0;r<4;r++){
        float v = acc[mi][nj][r] + bv[nj];
        if (OUT_BF16) ((short*)Cv)[(size_t)(row+r)*N + col] = f2bf(v);
        else          ((float*)Cv)[(size_t)(row+r)*N + col] = v;
      }
    }
  }
}

// ---------------- balanced, async-pipelined causal GQA attention ----------
// 256 threads (4 waves x 16 q rows). Block = pair of q-tiles (qi, 31-qi) at
// BQ=64 -> uniform 68 s-tile iters/block. 512 blocks x 4 waves = 2048 waves
// = 2 waves/SIMD (was 1 — latency-bound). Double-buffered LDS, K/V staged
// with global_load_lds into XOR-swizzled unpadded tiles, ONE barrier/iter.
// V swizzle includes ^((d>>2)&3) to break the l15 <-> l15+4 4-way bank alias
// on the b64 vf reads (both staging source and read slot use the same XOR).
// S^T = K*Q^T (16x16x32), P in registers, O^T += V^T*P^T (16x16x16).
__global__ __launch_bounds__(256) void k_attn(const short* __restrict__ qkv,
                                              const short* __restrict__ Vt,
                                              short* __restrict__ attn){
  constexpr float COEF = 0.12752365f;     // (1/sqrt(128)) * log2(e)
  __shared__ short SM[16384];             // 2 buffers x (K 4096 + V 4096 shorts)
  const int tid = threadIdx.x, w = tid >> 6, lane = tid & 63;
  const int l15 = lane & 15, quad = lane >> 4;
  const int p = blockIdx.x, h = blockIdx.y, b = blockIdx.z, kvh = h >> 2;

  // staging source pointers (per-lane); each wave stages 1/4 of each tile
  const short* kb[2];
  const short* vb[2];
#pragma unroll
  for (int j=0;j<2;j++){
    int rK = w*8 + j*4 + (lane >> 4);            // s-row 0..31
    int cK = (lane & 15) ^ (rK & 15);            // 8-short chunk of d
    kb[j] = qkv + (size_t)(b*2048 + rK)*3072 + 2048 + kvh*128 + cK*8;
    int dV = w*32 + j*16 + (lane >> 2);          // d-row 0..127
    int cV = (lane & 3) ^ (dV & 3) ^ ((dV >> 2) & 3);  // 8-short chunk of s
    vb[j] = Vt + ((size_t)((b*4 + kvh)*128 + dV))*2048 + cV*8;
  }
  short* K0 = &SM[w*1024];                // wave's slot base, buf 0
  short* V0 = &SM[4096 + w*1024];

  int buf = 0;
  // prologue: stage tile 0 of strip 0 into buf 0
#pragma unroll
  for (int j=0;j<2;j++){
    gld16(K0 + j*512, kb[j]);
    gld16(V0 + j*512, vb[j]);
  }

  for (int sp = 0; sp < 2; sp++){
    const int qi = sp ? (31 - p) : p;
    const int qw = qi*64 + w*16;          // this wave's 16 q rows
    // Q fragments from global (B-operand layout: lane q=l15, k contiguous)
    bf16x8 qf[4];
    {
      const short* qbase = qkv + ((size_t)(b*2048 + qw + l15))*3072 + h*128 + quad*8;
#pragma unroll
      for (int d4=0;d4<4;d4++)
        qf[d4] = *(const bf16x8*)(qbase + d4*32);
    }
    f32x4 accO[8] = {};
    float lsum = 0.f;
    const int nst = 2*qi + 2;

    for (int st = 0; st < nst; st++){
      __syncthreads();                       // tile(st) in LDS[buf] complete
      const int cur = buf;
      const int nb = buf ^ 1;
      // async-stage next tile (or next strip's tile 0) into other buffer
      {
        int nxt = -1;
        if (st + 1 < nst) nxt = (st + 1) * 32;
        else if (sp == 0) nxt = 0;
        if (nxt >= 0){
          short* Kd = &SM[nb*8192 + w*1024];
          short* Vd = &SM[nb*8192 + 4096 + w*1024];
          const size_t ko = (size_t)nxt * 3072;
#pragma unroll
          for (int j=0;j<2;j++){
            gld16(Kd + j*512, kb[j] + ko);
            gld16(Vd + j*512, vb[j] + nxt);
          }
        }
      }
      const int s0 = st * 32;
      if (s0 <= qw + 15){                    // wave-uniform skip
        const short* Kb = &SM[cur*8192];
        const short* Vb = &SM[cur*8192 + 4096];
        bf16x8 kf[2][4];
#pragma unroll
        for (int ss=0;ss<2;ss++)
#pragma unroll
          for (int d4=0;d4<4;d4++){
            int slot = (ss*16 + l15)*16 + ((d4*4 + quad) ^ l15);
            kf[ss][d4] = *(const bf16x8*)&Kb[slot*8];
          }
        f32x4 sa[2] = {};
#pragma unroll
        for (int d4=0;d4<4;d4++){
          sa[0] = MFMA16(kf[0][d4], qf[d4], sa[0]);
          sa[1] = MFMA16(kf[1][d4], qf[d4], sa[1]);
        }
        short4v pf[2];
        const bool mneed = (s0 + 31 > qw);
        const int qgl = qw + l15;
#pragma unroll
        for (int sub=0;sub<2;sub++){
          float pr[4];
#pragma unroll
          for (int r=0;r<4;r++){
            float e = __builtin_amdgcn_exp2f(sa[sub][r] * COEF);
            int sg = s0 + sub*16 + quad*4 + r;
            if (mneed && (sg > qgl)) e = 0.f;
            pr[r] = e;
          }
          lsum += (pr[0]+pr[1]) + (pr[2]+pr[3]);
          union { unsigned u[2]; short4v s; } pk;
          pk.u[0] = __builtin_amdgcn_perm(bits(pr[1]), bits(pr[0]), 0x07060302u);
          pk.u[1] = __builtin_amdgcn_perm(bits(pr[3]), bits(pr[2]), 0x07060302u);
          pf[sub] = pk.s;
        }
        // O^T += V^T * P^T
#pragma unroll
        for (int sub=0;sub<2;sub++)
#pragma unroll
          for (int dt=0;dt<8;dt++){
            int slot = (dt*16 + l15)*4 +
                       ((sub*2 + (quad>>1)) ^ (l15 & 3) ^ ((l15 >> 2) & 3));
            short4v vf = *(const short4v*)&Vb[slot*8 + (quad&1)*4];
            accO[dt] = MFMA16K(vf, pf[sub], accO[dt]);
          }
      }
      buf = nb;
    }
    // normalize + store this strip
    {
      float s = lsum;
      s += __shfl_xor(s, 16);
      s += __shfl_xor(s, 32);
      float inv = 1.0f / s;
      short* obase = attn + ((size_t)(b*2048 + qw + l15))*2048 + h*128 + quad*4;
#pragma unroll
      for (int dt=0;dt<8;dt++){
        float o0 = accO[dt][0]*inv, o1 = accO[dt][1]*inv;
        float o2 = accO[dt][2]*inv, o3 = accO[dt][3]*inv;
        union { unsigned u[2]; short4v s; } ok;
        ok.u[0] = __builtin_amdgcn_perm(bits(o1), bits(o0), 0x07060302u);
        ok.u[1] = __builtin_amdgcn_perm(bits(o3), bits(o2), 0x07060302u);
        *(short4v*)(obase + dt*16) = ok.s;
      }
    }
  }
}

// ---------------- launcher ----------------
extern "C" void kernel_launch(void* const* d_in, const int* in_sizes, int n_in,
                              void* d_out, int out_size, void* d_ws, size_t ws_size,
                              hipStream_t stream){
  const float* x  = (const float*)d_in[0];
  const float* Wq = (const float*)d_in[1];
  const float* bq = (const float*)d_in[2];
  const float* Wk = (const float*)d_in[3];
  const float* bk = (const float*)d_in[4];
  const float* Wv = (const float*)d_in[5];
  const float* bv = (const float*)d_in[6];
  const float* Wo = (const float*)d_in[7];
  const float* bo = (const float*)d_in[8];
  float* out = (float*)d_out;
  char* ws = (char*)d_ws;

  short* xb    = (short*)(ws + 0);                        // 16 MB
  short* WtQKV = (short*)(ws + (size_t)16*1024*1024);     // 12 MB [3072][2048]
  short* WoT   = (short*)(ws + (size_t)28*1024*1024);     //  8 MB [2048][2048]
  float* biasQ = (float*)(ws + (size_t)36*1024*1024);     // 12 KB
  short* qkv   = (short*)(ws + (size_t)37*1024*1024);     // 24 MB [4096][3072]
  short* Vt    = (short*)(ws + (size_t)61*1024*1024);     //  4 MB [B][KVH][128][2048]
  short* attn  = (short*)(ws + 0);                        // overlay xb (disjoint lifetime)

  k_cvt8<<<4096, 256, 0, stream>>>(x, xb);
  k_wt<<<dim3(64,64), dim3(32,8), 0, stream>>>(Wq, WtQKV, 2048);
  k_wt<<<dim3(16,64), dim3(32,8), 0, stream>>>(Wk, WtQKV + (size_t)2048*2048, 512);
  k_wt<<<dim3(16,64), dim3(32,8), 0, stream>>>(Wv, WtQKV + (size_t)2560*2048, 512);
  k_wt<<<dim3(64,64), dim3(32,8), 0, stream>>>(Wo, WoT, 2048);
  k_bias<<<12, 256, 0, stream>>>(bq, bk, bv, biasQ);
  gemm_bt<1><<<dim3(24,32), 256, 0, stream>>>(xb, WtQKV, biasQ, qkv, 4096, 3072, 2048);
  k_vt<<<dim3(128,16), dim3(32,8), 0, stream>>>(qkv, Vt);
  k_attn<<<dim3(16,16,2), 256, 0, stream>>>(qkv, Vt, attn);
  gemm_bt<0><<<dim3(16,32), 256, 0, stream>>>(attn, WoT, bo, out, 4096, 2048, 2048);
}